// Round 15
// baseline (170.671 us; speedup 1.0000x reference)
//
#include <hip/hip_runtime.h>
#include <hip/hip_bf16.h>

#define NN 4096
#define EDIM 256
#define NHEAD 4
#define DH 64
#define NEDGE 131072
#define NE (NN * EDIM)
#define NSPLIT 8
#define KEYS_PER_SPLIT (NN / NSPLIT)
#define QKS 512   // qkv row stride (Q|K only; V goes straight to vtb)
#define QSCL 0.18033688011112042f   // (1/8) * log2(e): folds softmax exp->exp2

typedef __bf16 bf16x8 __attribute__((ext_vector_type(8)));
typedef float f32x4 __attribute__((ext_vector_type(4)));
typedef float f32x16 __attribute__((ext_vector_type(16)));

__device__ inline void gload_lds16(const void* g, void* l) {
    __builtin_amdgcn_global_load_lds((const __attribute__((address_space(1))) unsigned int*)g,
                                     (__attribute__((address_space(3))) unsigned int*)l, 16, 0, 0);
}

// -------- one-time prep: weights->bf16 (q rows pre-scaled), x->bf16, degi=0 -
__global__ __launch_bounds__(256) void prep_kernel(
    const float* __restrict__ wl, const float* __restrict__ siw, const float* __restrict__ sib,
    const float* __restrict__ sow, const float* __restrict__ ciw, const float* __restrict__ cib,
    const float* __restrict__ cow, const float* __restrict__ gw, const float* __restrict__ fw,
    const float* __restrict__ x,
    __bf16* __restrict__ siwb, __bf16* __restrict__ ciwb, __bf16* __restrict__ sowb,
    __bf16* __restrict__ cowb, __bf16* __restrict__ gwb, __bf16* __restrict__ fwb,
    __bf16* __restrict__ wlT, __bf16* __restrict__ xb,
    float* __restrict__ sib_adj, float* __restrict__ cib_adj, int* __restrict__ degi) {
    long i = (long)blockIdx.x * 256 + threadIdx.x;
    if (i < 196608) { float v = siw[i]; if (i < 65536) v *= QSCL; siwb[i] = (__bf16)v; return; }
    i -= 196608;
    if (i < 196608) { float v = ciw[i]; if (i < 65536) v *= QSCL; ciwb[i] = (__bf16)v; return; }
    i -= 196608;
    if (i < 65536) { sowb[i] = (__bf16)sow[i]; return; }
    i -= 65536;
    if (i < 65536) { cowb[i] = (__bf16)cow[i]; return; }
    i -= 65536;
    if (i < 131072) { gwb[i] = (__bf16)gw[i]; return; }
    i -= 131072;
    if (i < 65536) { fwb[i] = (__bf16)fw[i]; return; }
    i -= 65536;
    if (i < 65536) { int n = (int)(i >> 8), k = (int)(i & 255); wlT[i] = (__bf16)wl[k * 256 + n]; return; }
    i -= 65536;
    if (i < 1048576) { xb[i] = (__bf16)x[i]; return; }
    i -= 1048576;
    if (i < 768) { sib_adj[i] = sib[i] * (i < 256 ? QSCL : 1.f); return; }
    i -= 768;
    if (i < 768) { cib_adj[i] = cib[i] * (i < 256 ? QSCL : 1.f); return; }
    i -= 768;
    if (i < 4096) degi[i] = 0;
}

// ---------------- GCN: CSR build + gather ----------------
__global__ __launch_bounds__(256) void degi_kernel(const int* __restrict__ ei,
                                                   int* __restrict__ degi, int ne) {
    int e = blockIdx.x * 256 + threadIdx.x;
    if (e < ne) atomicAdd(&degi[ei[ne + e]], 1);  // col = ei[1][e]
}

__global__ __launch_bounds__(256) void scan_kernel(const int* __restrict__ degi,
                                                   int* __restrict__ off,
                                                   int* __restrict__ cursor,
                                                   float* __restrict__ dnz) {
    __shared__ int s[256];
    const int t = threadIdx.x, i0 = t * 16;
    int v[16], sum = 0;
#pragma unroll
    for (int j = 0; j < 16; ++j) { v[j] = degi[i0 + j]; sum += v[j]; }
    s[t] = sum;
    __syncthreads();
#pragma unroll
    for (int d = 1; d < 256; d <<= 1) {
        int add = (t >= d) ? s[t - d] : 0;
        __syncthreads();
        s[t] += add;
        __syncthreads();
    }
    int base = s[t] - sum;
#pragma unroll
    for (int j = 0; j < 16; ++j) {
        off[i0 + j] = base;
        cursor[i0 + j] = base;
        dnz[i0 + j] = (v[j] > 0) ? rsqrtf((float)v[j]) : 0.f;
        base += v[j];
    }
}

__global__ __launch_bounds__(256) void fill_kernel(const int* __restrict__ ei,
                                                   int* __restrict__ cursor,
                                                   int* __restrict__ rows, int ne) {
    int e = blockIdx.x * 256 + threadIdx.x;
    if (e < ne) {
        int r = ei[e], c = ei[ne + e];
        int pos = atomicAdd(&cursor[c], 1);
        rows[pos] = r;
    }
}

__global__ __launch_bounds__(256) void gather_kernel(const int* __restrict__ off,
                                                     const int* __restrict__ rows,
                                                     const float* __restrict__ dnz,
                                                     const __bf16* __restrict__ xb,
                                                     __bf16* __restrict__ hib) {
    __shared__ float sm[2][256];
    const int c = blockIdx.x, t = threadIdx.x;
    const int half = t >> 7, c2 = (t & 127) * 2;
    const int s0 = off[c];
    const int s1 = (c == NN - 1) ? NEDGE : off[c + 1];
    float a0 = 0.f, a1 = 0.f;
    for (int j = s0 + half; j < s1; j += 2) {
        int r = rows[j];
        float dv = dnz[r];
        unsigned int pk = *(const unsigned int*)&xb[(size_t)r * EDIM + c2];
        a0 += dv * __uint_as_float(pk << 16);
        a1 += dv * __uint_as_float(pk & 0xffff0000u);
    }
    sm[half][c2] = a0;
    sm[half][c2 + 1] = a1;
    __syncthreads();
    float v = (sm[0][t] + sm[1][t]) * dnz[c];
    hib[(size_t)c * EDIM + t] = (__bf16)v;
}

// ------- shared bf16 GEMM core, double-buffered LDS pipeline (BK=64) -------
__device__ inline void gemm_core(const __bf16* __restrict__ A, int lda,
                                 const __bf16* __restrict__ Bt, int ldb,
                                 int row0, int col0, int K, int tid,
                                 __bf16* As, __bf16* Bs, f32x4 acc[4]) {
    const int w = tid >> 6, l = tid & 63, lr = l & 15, lk = l >> 4;
    const int srow = (l >> 3), scol = (l & 7) * 8;
    auto stage = [&](int k0, int buf) {
#pragma unroll
        for (int cc = 0; cc < 2; ++cc) {
            int E0 = (w * 2 + cc) * 512;
            int row = (E0 >> 6) + srow;
            int sc = scol ^ ((row & 7) << 3);
            gload_lds16(A + (size_t)(row0 + row) * lda + k0 + sc, &As[buf * 4096 + E0]);
            gload_lds16(Bt + (size_t)(col0 + row) * ldb + k0 + sc, &Bs[buf * 4096 + E0]);
        }
    };
    stage(0, 0);
    __syncthreads();
    int buf = 0;
    for (int k0 = 0; k0 < K; k0 += 64) {
        if (k0 + 64 < K) stage(k0 + 64, buf ^ 1);
#pragma unroll
        for (int ks = 0; ks < 2; ++ks) {
            int cswz = (ks * 32 + lk * 8) ^ ((lr & 7) << 3);
            bf16x8 af = *(bf16x8*)&As[buf * 4096 + (w * 16 + lr) * 64 + cswz];
#pragma unroll
            for (int nt = 0; nt < 4; ++nt) {
                bf16x8 bfr = *(bf16x8*)&Bs[buf * 4096 + (nt * 16 + lr) * 64 + cswz];
                acc[nt] = __builtin_amdgcn_mfma_f32_16x16x32_bf16(af, bfr, acc[nt], 0, 0, 0);
            }
        }
        __syncthreads();
        buf ^= 1;
    }
}

// ---- thin bf16 GEMM: 16x64 tile, grid (Nc/64, M/16) -> 4 blocks/CU --------
template <bool RELU, bool OUTBF>
__global__ __launch_bounds__(256) void gemm_thin(const __bf16* __restrict__ A,
                                                 const __bf16* __restrict__ A2, int lda,
                                                 const __bf16* __restrict__ Bt, int ldb,
                                                 const float* __restrict__ bias,
                                                 void* __restrict__ Cv, int ldc, int K) {
    __shared__ __align__(16) __bf16 As[2 * 1024];
    __shared__ __align__(16) __bf16 Bs[2 * 4096];
    const int tid = threadIdx.x;
    const int row0 = blockIdx.y * 16, col0 = blockIdx.x * 64;
    const int w = tid >> 6, l = tid & 63, lr = l & 15, lk = l >> 4;
    const int srow = l >> 3, scol = (l & 7) * 8;
    f32x4 acc = {};
    auto stage = [&](int k0, int buf) {
        const __bf16* Asrc = A;
        int ka = k0;
        if (A2 != nullptr && k0 >= 256) { Asrc = A2; ka = k0 - 256; }
#pragma unroll
        for (int cc = 0; cc < 2; ++cc) {
            int E0 = (w * 2 + cc) * 512;
            int row = (E0 >> 6) + srow;
            int sc = scol ^ ((row & 7) << 3);
            gload_lds16(Bt + (size_t)(col0 + row) * ldb + k0 + sc, &Bs[buf * 4096 + E0]);
        }
        if (w < 2) {
            int E0 = w * 512;
            int row = (E0 >> 6) + srow;
            int sc = scol ^ ((row & 7) << 3);
            gload_lds16(Asrc + (size_t)(row0 + row) * lda + ka + sc, &As[buf * 1024 + E0]);
        }
    };
    stage(0, 0);
    __syncthreads();
    int buf = 0;
    for (int k0 = 0; k0 < K; k0 += 64) {
        if (k0 + 64 < K) stage(k0 + 64, buf ^ 1);
#pragma unroll
        for (int ks = 0; ks < 2; ++ks) {
            int cswz = (ks * 32 + lk * 8) ^ ((lr & 7) << 3);
            bf16x8 af = *(bf16x8*)&As[buf * 1024 + lr * 64 + cswz];
            bf16x8 bfr = *(bf16x8*)&Bs[buf * 4096 + (w * 16 + lr) * 64 + cswz];
            acc = __builtin_amdgcn_mfma_f32_16x16x32_bf16(af, bfr, acc, 0, 0, 0);
        }
        __syncthreads();
        buf ^= 1;
    }
    float bv = bias ? bias[col0 + w * 16 + lr] : 0.f;
#pragma unroll
    for (int r = 0; r < 4; ++r) {
        float v = acc[r] + bv;
        if (RELU) v = fmaxf(v, 0.f);
        size_t ci = (size_t)(row0 + lk * 4 + r) * ldc + col0 + w * 16 + lr;
        if (OUTBF) ((__bf16*)Cv)[ci] = (__bf16)v;
        else ((float*)Cv)[ci] = v;
    }
}

// ---------------- shared epilogue: qkv cols -> qkv (Q|K) or vtb (V^T) ------
__device__ inline void qkv_epilogue(f32x4 acc[4], const float* __restrict__ bias,
                                    int gcol0, int row0, int tid,
                                    __bf16* __restrict__ qkv, __bf16* __restrict__ vtb) {
    const int w = tid >> 6, l = tid & 63, lr = l & 15, lk = l >> 4;
    if (gcol0 < 512) {
#pragma unroll
        for (int nt = 0; nt < 4; ++nt) {
            float bv = bias[gcol0 + nt * 16 + lr];
#pragma unroll
            for (int r = 0; r < 4; ++r)
                qkv[(size_t)(row0 + w * 16 + lk * 4 + r) * QKS + gcol0 + nt * 16 + lr] =
                    (__bf16)(acc[nt][r] + bv);
        }
    } else {
        const int n4 = row0 + w * 16 + lk * 4;
#pragma unroll
        for (int nt = 0; nt < 4; ++nt) {
            int dg = gcol0 - 512 + nt * 16 + lr;      // 0..255 = h*64+d
            float bv = bias[gcol0 + nt * 16 + lr];
            union { __bf16 b[4]; ushort4 u; } pk;
#pragma unroll
            for (int r = 0; r < 4; ++r) pk.b[r] = (__bf16)(acc[nt][r] + bv);
            *(ushort4*)&vtb[(size_t)dg * NN + n4] = pk.u;
        }
    }
}

// ---------------- fused: local_embed GEMM + SA qkv GEMM (one dispatch) -----
__global__ __launch_bounds__(256) void fused_local_qkv(
    const __bf16* __restrict__ hi_bf, const __bf16* __restrict__ x_bf,
    const __bf16* __restrict__ wlT, const __bf16* __restrict__ siwb,
    const float* __restrict__ sib,
    __bf16* __restrict__ local_bf, __bf16* __restrict__ qkv, __bf16* __restrict__ vtb) {
    __shared__ __align__(16) __bf16 As[2 * 4096];
    __shared__ __align__(16) __bf16 Bs[2 * 4096];
    const int tid = threadIdx.x;
    const int bx = blockIdx.x, row0 = blockIdx.y * 64;
    f32x4 acc[4] = {};
    if (bx < 4) {
        gemm_core(hi_bf, 256, wlT, 256, row0, bx * 64, 256, tid, As, Bs, acc);
        const int w = tid >> 6, l = tid & 63, lr = l & 15, lk = l >> 4;
#pragma unroll
        for (int nt = 0; nt < 4; ++nt)
#pragma unroll
            for (int r = 0; r < 4; ++r)
                local_bf[(size_t)(row0 + w * 16 + lk * 4 + r) * 256 + bx * 64 + nt * 16 + lr] =
                    (__bf16)acc[nt][r];
    } else {
        const int gcol0 = (bx - 4) * 64;
        gemm_core(x_bf, 256, siwb, 256, row0, gcol0, 256, tid, As, Bs, acc);
        qkv_epilogue(acc, sib, gcol0, row0, tid, qkv, vtb);
    }
}

// ---------------- fused: CA q-proj + CA kv-proj (one dispatch) -------------
__global__ __launch_bounds__(256) void fused_cross_proj(
    const __bf16* __restrict__ global_bf, const __bf16* __restrict__ local_bf,
    const __bf16* __restrict__ ciwb, const float* __restrict__ cib,
    __bf16* __restrict__ qkv, __bf16* __restrict__ vtb) {
    __shared__ __align__(16) __bf16 As[2 * 4096];
    __shared__ __align__(16) __bf16 Bs[2 * 4096];
    const int tid = threadIdx.x;
    const int bx = blockIdx.x, row0 = blockIdx.y * 64;
    const int gcol0 = (bx < 4) ? bx * 64 : 256 + (bx - 4) * 64;
    const __bf16* A = (bx < 4) ? global_bf : local_bf;
    f32x4 acc[4] = {};
    gemm_core(A, 256, ciwb, 256, row0, gcol0, 256, tid, As, Bs, acc);
    qkv_epilogue(acc, cib, gcol0, row0, tid, qkv, vtb);
}

// ------- flash attention, split-KV, 32x32 MFMA, in-register softmax --------
// Row-sum via MFMA ones-trick: sum_acc = mfma(ones, P^T) accumulates the
// softmax denominator on the matrix pipe (removes 32 VALU adds/lane/tile
// and the fp32 p[] array; every D-row equals the per-query sum).
__global__ __launch_bounds__(256, 4) void attn_split(const __bf16* __restrict__ qkvb,
                                                     const __bf16* __restrict__ Vtb,
                                                     __bf16* __restrict__ p0,
                                                     __bf16* __restrict__ p1,
                                                     __bf16* __restrict__ p2,
                                                     __bf16* __restrict__ p3,
                                                     float* __restrict__ ml) {
    const int h = blockIdx.y, s = blockIdx.z;
    const int n0 = blockIdx.x * 128;
    const int tid = threadIdx.x;
    const int w = tid >> 6, l = tid & 63;
    const int qi = l & 31, hi = l >> 5, hi8 = hi * 8;
    const int swz = (l & 7) << 3;

    __shared__ __align__(16) __bf16 Kt[2 * 4096];   // [64 key][64 d] swizzled
    __shared__ __align__(16) __bf16 Vt[2 * 4096];   // [64 d][64 key] swizzled

    const int qrow = n0 + w * 32 + qi;
    bf16x8 qf[4];   // q pre-scaled by log2e/8
#pragma unroll
    for (int d0 = 0; d0 < 4; ++d0)
        qf[d0] = *(const bf16x8*)&qkvb[(size_t)qrow * QKS + h * 64 + d0 * 16 + hi8];

    bf16x8 ones;
#pragma unroll
    for (int i = 0; i < 8; ++i) ones[i] = (__bf16)1.0f;

    f32x16 ot0 = {}, ot1 = {}, sum_acc = {};
    const __bf16* Vbh = Vtb + (size_t)h * 64 * NN;
    const int srow = (l >> 3), scol = (l & 7) * 8;

    auto stageKV = [&](int t, int buf) {
        const int kv0 = s * KEYS_PER_SPLIT + t * 64;
#pragma unroll
        for (int cc = 0; cc < 2; ++cc) {
            int E0 = (w * 2 + cc) * 512;
            int row = (E0 >> 6) + srow;
            int sc = scol ^ ((row & 7) << 3);
            gload_lds16(qkvb + (size_t)(kv0 + row) * QKS + 256 + h * 64 + sc, &Kt[buf * 4096 + E0]);
            gload_lds16(Vbh + (size_t)row * NN + kv0 + sc, &Vt[buf * 4096 + E0]);
        }
    };

    stageKV(0, 0);
    __syncthreads();
    int buf = 0;
    for (int t = 0; t < KEYS_PER_SPLIT / 64; ++t) {
        if (t + 1 < KEYS_PER_SPLIT / 64) stageKV(t + 1, buf ^ 1);
#pragma unroll
        for (int ss = 0; ss < 2; ++ss) {
            f32x16 st = {};
#pragma unroll
            for (int d0 = 0; d0 < 4; ++d0) {
                bf16x8 kf = *(bf16x8*)&Kt[buf * 4096 + (ss * 32 + qi) * 64 + ((d0 * 16 + hi8) ^ swz)];
                st = __builtin_amdgcn_mfma_f32_32x32x16_bf16(kf, qf[d0], st, 0, 0, 0);
            }
            unsigned int wd[8];
#pragma unroll
            for (int j = 0; j < 8; ++j) {
                float a = exp2f(st[2 * j]);
                float b = exp2f(st[2 * j + 1]);
                asm("v_cvt_pk_bf16_f32 %0, %1, %2" : "=v"(wd[j]) : "v"(a), "v"(b));
            }
            asm("v_permlane32_swap_b32 %0, %1" : "+v"(wd[0]), "+v"(wd[2]));
            asm("v_permlane32_swap_b32 %0, %1" : "+v"(wd[1]), "+v"(wd[3]));
            asm("v_permlane32_swap_b32 %0, %1" : "+v"(wd[4]), "+v"(wd[6]));
            asm("v_permlane32_swap_b32 %0, %1" : "+v"(wd[5]), "+v"(wd[7]));
            union { unsigned int u[4]; bf16x8 v; } pa0, pa1;
            pa0.u[0] = wd[0]; pa0.u[1] = wd[1]; pa0.u[2] = wd[2]; pa0.u[3] = wd[3];
            pa1.u[0] = wd[4]; pa1.u[1] = wd[5]; pa1.u[2] = wd[6]; pa1.u[3] = wd[7];
            sum_acc = __builtin_amdgcn_mfma_f32_32x32x16_bf16(ones, pa0.v, sum_acc, 0, 0, 0);
            sum_acc = __builtin_amdgcn_mfma_f32_32x32x16_bf16(ones, pa1.v, sum_acc, 0, 0, 0);
#pragma unroll
            for (int kt = 0; kt < 2; ++kt) {
                bf16x8 pav = kt ? pa1.v : pa0.v;
                int colk = (ss * 32 + kt * 16 + hi8) ^ swz;
                bf16x8 vf0 = *(bf16x8*)&Vt[buf * 4096 + qi * 64 + colk];
                bf16x8 vf1 = *(bf16x8*)&Vt[buf * 4096 + (32 + qi) * 64 + colk];
                ot0 = __builtin_amdgcn_mfma_f32_32x32x16_bf16(vf0, pav, ot0, 0, 0, 0);
                ot1 = __builtin_amdgcn_mfma_f32_32x32x16_bf16(vf1, pav, ot1, 0, 0, 0);
            }
        }
        __syncthreads();
        buf ^= 1;
    }

    float tot = sum_acc[0];   // every D-row of (ones @ P^T) equals the q-sum
    __bf16* pb;
    switch (s >> 1) {
        case 0: pb = p0; break;
        case 1: pb = p1; break;
        case 2: pb = p2; break;
        default: pb = p3; break;
    }
    pb += (size_t)(s & 1) * NHEAD * NN * 64;

    // O^T regs -> wave-local LDS (swizzled), then 1KB-contiguous global stores
    __bf16* lw = &Kt[w * 2048];      // Kt dead after the loop
    const int sw = (qi & 7) << 3;
#pragma unroll
    for (int r = 0; r < 16; r += 2) {
        int d = (r & 3) + 8 * (r >> 2) + 4 * hi;   // even; pairs (d, d+1)
        union { unsigned int u; __bf16 b[2]; } w2, w3;
        w2.b[0] = (__bf16)ot0[r]; w2.b[1] = (__bf16)ot0[r + 1];
        w3.b[0] = (__bf16)ot1[r]; w3.b[1] = (__bf16)ot1[r + 1];
        *(unsigned int*)&lw[qi * 64 + (d ^ sw)] = w2.u;
        *(unsigned int*)&lw[qi * 64 + ((d + 32) ^ sw)] = w3.u;
    }
    if (hi == 0) ml[((size_t)s * NHEAD + h) * NN + qrow] = tot;
    __syncthreads();
    __bf16* gdst = pb + ((size_t)h * NN + n0 + w * 32) * 64;
#pragma unroll
    for (int j = 0; j < 4; ++j) {
        int q = (l >> 3) + j * 8;
        int x = (l & 7) * 8;
        bf16x8 v = *(bf16x8*)&lw[q * 64 + (x ^ ((q & 7) << 3))];
        *(bf16x8*)&gdst[q * 64 + x] = v;
    }
}

// ---------------- merge: core[n][h*64+d] = sum_s part / sum_s l ------------
__global__ __launch_bounds__(256) void attn_merge(const __bf16* __restrict__ p0,
                                                  const __bf16* __restrict__ p1,
                                                  const __bf16* __restrict__ p2,
                                                  const __bf16* __restrict__ p3,
                                                  const float* __restrict__ ml,
                                                  __bf16* __restrict__ coreb) {
    int g = blockIdx.x * 256 + threadIdx.x;     // 0 .. NHEAD*NN*8-1
    int d8 = g & 7;
    int hn = g >> 3;                            // h*NN + n
    int n = hn & (NN - 1), h = hn >> 12;
    float L = 0.f;
    float o[8] = {};
#pragma unroll
    for (int s = 0; s < NSPLIT; ++s) {
        const __bf16* pb = (s < 2 ? p0 : s < 4 ? p1 : s < 6 ? p2 : p3) +
                           (size_t)(s & 1) * NHEAD * NN * 64;
        bf16x8 v = *(const bf16x8*)&pb[(size_t)hn * 64 + d8 * 8];
#pragma unroll
        for (int j = 0; j < 8; ++j) o[j] += (float)v[j];
        L += ml[((size_t)s * NHEAD + h) * NN + n];
    }
    float inv = 1.f / L;
    bf16x8 r;
#pragma unroll
    for (int j = 0; j < 8; ++j) r[j] = (__bf16)(o[j] * inv);
    *(bf16x8*)&coreb[(size_t)n * 256 + h * 64 + d8 * 8] = r;
}

// ---------------- LayerNorm(a + b) -> fp32 and/or bf16 ----------------
__device__ inline float block_sum256(float v, float* tmp) {
#pragma unroll
    for (int o = 32; o; o >>= 1) v += __shfl_xor(v, o);
    __syncthreads();
    if ((threadIdx.x & 63) == 0) tmp[threadIdx.x >> 6] = v;
    __syncthreads();
    return tmp[0] + tmp[1] + tmp[2] + tmp[3];
}

__global__ __launch_bounds__(256) void ln_kernel(const float* __restrict__ a,
                                                 const float* __restrict__ b,
                                                 const float* __restrict__ g,
                                                 const float* __restrict__ be,
                                                 float* __restrict__ outf,
                                                 __bf16* __restrict__ outb) {
    __shared__ float tmp[4];
    const int n = blockIdx.x, t = threadIdx.x;
    float v = a[n * EDIM + t] + b[n * EDIM + t];
    float mean = block_sum256(v, tmp) * (1.f / 256.f);
    float c = v - mean;
    float var = block_sum256(c * c, tmp) * (1.f / 256.f);
    float o = c * (1.f / sqrtf(var + 1e-5f)) * g[t] + be[t];
    if (outf) outf[n * EDIM + t] = o;
    if (outb) outb[n * EDIM + t] = (__bf16)o;
}

extern "C" void kernel_launch(void* const* d_in, const int* in_sizes, int n_in,
                              void* d_out, int out_size, void* d_ws, size_t ws_size,
                              hipStream_t stream) {
    const float* x = (const float*)d_in[0];
    const int* ei = (const int*)d_in[1];
    const float* w_local = (const float*)d_in[2];
    const float* sa_in_w = (const float*)d_in[3];
    const float* sa_in_b = (const float*)d_in[4];
    const float* sa_out_w = (const float*)d_in[5];
    const float* sa_out_b = (const float*)d_in[6];
    const float* ln1_g = (const float*)d_in[7];
    const float* ln1_b = (const float*)d_in[8];
    const float* ca_in_w = (const float*)d_in[9];
    const float* ca_in_b = (const float*)d_in[10];
    const float* ca_out_w = (const float*)d_in[11];
    const float* ca_out_b = (const float*)d_in[12];
    const float* ln2_g = (const float*)d_in[13];
    const float* ln2_b = (const float*)d_in[14];
    const float* gate_w = (const float*)d_in[15];
    const float* gate_b = (const float*)d_in[16];
    const float* fc_w = (const float*)d_in[17];
    const float* fc_b = (const float*)d_in[18];
    float* out = (float*)d_out;

    float* ws = (float*)d_ws;
    float* dnz = ws;                                   // 4096
    float* ml = ws + 4096;                             // 131072
    __bf16* x_bf = (__bf16*)(ml + 131072);             // NE bf16
    __bf16* hi_bf = (__bf16*)((float*)x_bf + NE / 2);  // NE bf16
    __bf16* local_bf = (__bf16*)((float*)hi_bf + NE / 2);
    __bf16* qkv_bf = (__bf16*)((float*)local_bf + NE / 2);  // 2*NE bf16 (stride 512)
    __bf16* core_bf = (__bf16*)((float*)qkv_bf + 3 * NE / 2);
    float* proj = (float*)core_bf + NE / 2;            // NE f32
    float* global_f = proj + NE;                       // NE f32
    __bf16* global_bf = (__bf16*)(global_f + NE);      // NE bf16
    __bf16* aligned_bf = (__bf16*)((float*)global_bf + NE / 2);
    __bf16* fin_bf = (__bf16*)((float*)aligned_bf + NE / 2);
    __bf16* vtb = (__bf16*)((float*)fin_bf + NE / 2);  // NHEAD*NN*64 bf16
    __bf16* siwb = (__bf16*)((float*)vtb + NE / 2);    // 196608
    __bf16* ciwb = siwb + 196608;
    __bf16* sowb = ciwb + 196608;
    __bf16* cowb = sowb + 65536;
    __bf16* gwb = cowb + 65536;
    __bf16* fwb = gwb + 131072;
    __bf16* wlT = fwb + 65536;
    float* sib_adj = (float*)(wlT + 65536);
    float* cib_adj = sib_adj + 768;

    // CSR scratch overlays qkv region (dead until in-proj GEMMs)
    int* degi = (int*)qkv_bf;
    int* off = degi + 4096;
    int* cursor = off + 4096;
    int* rows = cursor + 4096;

    // attention split partials: 4 regions x 2 splits x 2MB ([h][n][64] each)
    __bf16* pA = (__bf16*)out;
    __bf16* pB = x_bf;
    __bf16* pC = (__bf16*)proj;
    __bf16* pD = aligned_bf;

    // ---- prep (weights/x -> bf16, degi zero) ----
    prep_kernel<<<7190, 256, 0, stream>>>(w_local, sa_in_w, sa_in_b, sa_out_w,
                                          ca_in_w, ca_in_b, ca_out_w, gate_w, fc_w, x,
                                          siwb, ciwb, sowb, cowb, gwb, fwb, wlT, x_bf,
                                          sib_adj, cib_adj, degi);

    // ---- GCN via CSR gather (bf16 x) ----
    degi_kernel<<<NEDGE / 256, 256, 0, stream>>>(ei, degi, NEDGE);
    scan_kernel<<<1, 256, 0, stream>>>(degi, off, cursor, dnz);
    fill_kernel<<<NEDGE / 256, 256, 0, stream>>>(ei, cursor, rows, NEDGE);
    gather_kernel<<<NN, 256, 0, stream>>>(off, rows, dnz, x_bf, hi_bf);

    // ---- local_embed GEMM + SA in-proj (fused dispatch; V -> vtb direct) ----
    fused_local_qkv<<<dim3(16, 64), 256, 0, stream>>>(
        hi_bf, x_bf, wlT, siwb, sib_adj, local_bf, qkv_bf, vtb);
    attn_split<<<dim3(NN / 128, NHEAD, NSPLIT), 256, 0, stream>>>(qkv_bf, vtb, pA, pB, pC, pD, ml);
    attn_merge<<<512, 256, 0, stream>>>(pA, pB, pC, pD, ml, core_bf);
    gemm_thin<false, false><<<dim3(4, 256), 256, 0, stream>>>(
        core_bf, nullptr, 256, sowb, 256, sa_out_b, proj, 256, 256);
    ln_kernel<<<NN, 256, 0, stream>>>(x, proj, ln1_g, ln1_b, global_f, global_bf);

    // ---- CA in-proj (fused q+kv dispatch) ----
    fused_cross_proj<<<dim3(12, 64), 256, 0, stream>>>(
        global_bf, local_bf, ciwb, cib_adj, qkv_bf, vtb);
    attn_split<<<dim3(NN / 128, NHEAD, NSPLIT), 256, 0, stream>>>(qkv_bf, vtb, pA, pB, pC, pD, ml);
    attn_merge<<<512, 256, 0, stream>>>(pA, pB, pC, pD, ml, core_bf);
    gemm_thin<false, false><<<dim3(4, 256), 256, 0, stream>>>(
        core_bf, nullptr, 256, cowb, 256, ca_out_b, proj, 256, 256);
    ln_kernel<<<NN, 256, 0, stream>>>(global_f, proj, ln2_g, ln2_b, nullptr, aligned_bf);

    // ---- gated head (concat via A/A2 switch) ----
    gemm_thin<true, true><<<dim3(4, 256), 256, 0, stream>>>(
        global_bf, aligned_bf, 256, gwb, 512, gate_b, fin_bf, 256, 512);
    gemm_thin<false, false><<<dim3(4, 256), 256, 0, stream>>>(
        fin_bf, nullptr, 256, fwb, 256, fc_b, out, 256, 256);
}

// Round 16
// 166.200 us; speedup vs baseline: 1.0269x; 1.0269x over previous
//
#include <hip/hip_runtime.h>
#include <hip/hip_bf16.h>

#define NN 4096
#define EDIM 256
#define NHEAD 4
#define DH 64
#define NEDGE 131072
#define NE (NN * EDIM)
#define NSPLIT 8
#define KEYS_PER_SPLIT (NN / NSPLIT)
#define QKS 512   // qkv row stride (Q|K only; V goes straight to vtb)
#define QSCL 0.18033688011112042f   // (1/8) * log2(e): folds softmax exp->exp2

typedef __bf16 bf16x8 __attribute__((ext_vector_type(8)));
typedef float f32x4 __attribute__((ext_vector_type(4)));
typedef float f32x16 __attribute__((ext_vector_type(16)));

__device__ inline void gload_lds16(const void* g, void* l) {
    __builtin_amdgcn_global_load_lds((const __attribute__((address_space(1))) unsigned int*)g,
                                     (__attribute__((address_space(3))) unsigned int*)l, 16, 0, 0);
}

// -------- one-time prep: weights->bf16 (q rows pre-scaled), x->bf16, degi=0 -
__global__ __launch_bounds__(256) void prep_kernel(
    const float* __restrict__ wl, const float* __restrict__ siw, const float* __restrict__ sib,
    const float* __restrict__ sow, const float* __restrict__ ciw, const float* __restrict__ cib,
    const float* __restrict__ cow, const float* __restrict__ gw, const float* __restrict__ fw,
    const float* __restrict__ x,
    __bf16* __restrict__ siwb, __bf16* __restrict__ ciwb, __bf16* __restrict__ sowb,
    __bf16* __restrict__ cowb, __bf16* __restrict__ gwb, __bf16* __restrict__ fwb,
    __bf16* __restrict__ wlT, __bf16* __restrict__ xb,
    float* __restrict__ sib_adj, float* __restrict__ cib_adj, int* __restrict__ degi) {
    long i = (long)blockIdx.x * 256 + threadIdx.x;
    if (i < 196608) { float v = siw[i]; if (i < 65536) v *= QSCL; siwb[i] = (__bf16)v; return; }
    i -= 196608;
    if (i < 196608) { float v = ciw[i]; if (i < 65536) v *= QSCL; ciwb[i] = (__bf16)v; return; }
    i -= 196608;
    if (i < 65536) { sowb[i] = (__bf16)sow[i]; return; }
    i -= 65536;
    if (i < 65536) { cowb[i] = (__bf16)cow[i]; return; }
    i -= 65536;
    if (i < 131072) { gwb[i] = (__bf16)gw[i]; return; }
    i -= 131072;
    if (i < 65536) { fwb[i] = (__bf16)fw[i]; return; }
    i -= 65536;
    if (i < 65536) { int n = (int)(i >> 8), k = (int)(i & 255); wlT[i] = (__bf16)wl[k * 256 + n]; return; }
    i -= 65536;
    if (i < 1048576) { xb[i] = (__bf16)x[i]; return; }
    i -= 1048576;
    if (i < 768) { sib_adj[i] = sib[i] * (i < 256 ? QSCL : 1.f); return; }
    i -= 768;
    if (i < 768) { cib_adj[i] = cib[i] * (i < 256 ? QSCL : 1.f); return; }
    i -= 768;
    if (i < 4096) degi[i] = 0;
}

// ---------------- GCN: CSR build + gather ----------------
__global__ __launch_bounds__(256) void degi_kernel(const int* __restrict__ ei,
                                                   int* __restrict__ degi, int ne) {
    int e = blockIdx.x * 256 + threadIdx.x;
    if (e < ne) atomicAdd(&degi[ei[ne + e]], 1);  // col = ei[1][e]
}

__global__ __launch_bounds__(256) void scan_kernel(const int* __restrict__ degi,
                                                   int* __restrict__ off,
                                                   int* __restrict__ cursor,
                                                   float* __restrict__ dnz) {
    __shared__ int s[256];
    const int t = threadIdx.x, i0 = t * 16;
    int v[16], sum = 0;
#pragma unroll
    for (int j = 0; j < 16; ++j) { v[j] = degi[i0 + j]; sum += v[j]; }
    s[t] = sum;
    __syncthreads();
#pragma unroll
    for (int d = 1; d < 256; d <<= 1) {
        int add = (t >= d) ? s[t - d] : 0;
        __syncthreads();
        s[t] += add;
        __syncthreads();
    }
    int base = s[t] - sum;
#pragma unroll
    for (int j = 0; j < 16; ++j) {
        off[i0 + j] = base;
        cursor[i0 + j] = base;
        dnz[i0 + j] = (v[j] > 0) ? rsqrtf((float)v[j]) : 0.f;
        base += v[j];
    }
}

__global__ __launch_bounds__(256) void fill_kernel(const int* __restrict__ ei,
                                                   int* __restrict__ cursor,
                                                   int* __restrict__ rows, int ne) {
    int e = blockIdx.x * 256 + threadIdx.x;
    if (e < ne) {
        int r = ei[e], c = ei[ne + e];
        int pos = atomicAdd(&cursor[c], 1);
        rows[pos] = r;
    }
}

__global__ __launch_bounds__(256) void gather_kernel(const int* __restrict__ off,
                                                     const int* __restrict__ rows,
                                                     const float* __restrict__ dnz,
                                                     const __bf16* __restrict__ xb,
                                                     __bf16* __restrict__ hib) {
    __shared__ float sm[2][256];
    const int c = blockIdx.x, t = threadIdx.x;
    const int half = t >> 7, c2 = (t & 127) * 2;
    const int s0 = off[c];
    const int s1 = (c == NN - 1) ? NEDGE : off[c + 1];
    float a0 = 0.f, a1 = 0.f;
    for (int j = s0 + half; j < s1; j += 2) {
        int r = rows[j];
        float dv = dnz[r];
        unsigned int pk = *(const unsigned int*)&xb[(size_t)r * EDIM + c2];
        a0 += dv * __uint_as_float(pk << 16);
        a1 += dv * __uint_as_float(pk & 0xffff0000u);
    }
    sm[half][c2] = a0;
    sm[half][c2 + 1] = a1;
    __syncthreads();
    float v = (sm[0][t] + sm[1][t]) * dnz[c];
    hib[(size_t)c * EDIM + t] = (__bf16)v;
}

// ------- shared bf16 GEMM core, double-buffered LDS pipeline (BK=64) -------
__device__ inline void gemm_core(const __bf16* __restrict__ A, int lda,
                                 const __bf16* __restrict__ Bt, int ldb,
                                 int row0, int col0, int K, int tid,
                                 __bf16* As, __bf16* Bs, f32x4 acc[4]) {
    const int w = tid >> 6, l = tid & 63, lr = l & 15, lk = l >> 4;
    const int srow = (l >> 3), scol = (l & 7) * 8;
    auto stage = [&](int k0, int buf) {
#pragma unroll
        for (int cc = 0; cc < 2; ++cc) {
            int E0 = (w * 2 + cc) * 512;
            int row = (E0 >> 6) + srow;
            int sc = scol ^ ((row & 7) << 3);
            gload_lds16(A + (size_t)(row0 + row) * lda + k0 + sc, &As[buf * 4096 + E0]);
            gload_lds16(Bt + (size_t)(col0 + row) * ldb + k0 + sc, &Bs[buf * 4096 + E0]);
        }
    };
    stage(0, 0);
    __syncthreads();
    int buf = 0;
    for (int k0 = 0; k0 < K; k0 += 64) {
        if (k0 + 64 < K) stage(k0 + 64, buf ^ 1);
#pragma unroll
        for (int ks = 0; ks < 2; ++ks) {
            int cswz = (ks * 32 + lk * 8) ^ ((lr & 7) << 3);
            bf16x8 af = *(bf16x8*)&As[buf * 4096 + (w * 16 + lr) * 64 + cswz];
#pragma unroll
            for (int nt = 0; nt < 4; ++nt) {
                bf16x8 bfr = *(bf16x8*)&Bs[buf * 4096 + (nt * 16 + lr) * 64 + cswz];
                acc[nt] = __builtin_amdgcn_mfma_f32_16x16x32_bf16(af, bfr, acc[nt], 0, 0, 0);
            }
        }
        __syncthreads();
        buf ^= 1;
    }
}

// ---- thin bf16 GEMM: 16x64 tile, grid (Nc/64, M/16) -> 4 blocks/CU --------
template <bool RELU, bool OUTBF>
__global__ __launch_bounds__(256) void gemm_thin(const __bf16* __restrict__ A,
                                                 const __bf16* __restrict__ A2, int lda,
                                                 const __bf16* __restrict__ Bt, int ldb,
                                                 const float* __restrict__ bias,
                                                 void* __restrict__ Cv, int ldc, int K) {
    __shared__ __align__(16) __bf16 As[2 * 1024];
    __shared__ __align__(16) __bf16 Bs[2 * 4096];
    const int tid = threadIdx.x;
    const int row0 = blockIdx.y * 16, col0 = blockIdx.x * 64;
    const int w = tid >> 6, l = tid & 63, lr = l & 15, lk = l >> 4;
    const int srow = l >> 3, scol = (l & 7) * 8;
    f32x4 acc = {};
    auto stage = [&](int k0, int buf) {
        const __bf16* Asrc = A;
        int ka = k0;
        if (A2 != nullptr && k0 >= 256) { Asrc = A2; ka = k0 - 256; }
#pragma unroll
        for (int cc = 0; cc < 2; ++cc) {
            int E0 = (w * 2 + cc) * 512;
            int row = (E0 >> 6) + srow;
            int sc = scol ^ ((row & 7) << 3);
            gload_lds16(Bt + (size_t)(col0 + row) * ldb + k0 + sc, &Bs[buf * 4096 + E0]);
        }
        if (w < 2) {
            int E0 = w * 512;
            int row = (E0 >> 6) + srow;
            int sc = scol ^ ((row & 7) << 3);
            gload_lds16(Asrc + (size_t)(row0 + row) * lda + ka + sc, &As[buf * 1024 + E0]);
        }
    };
    stage(0, 0);
    __syncthreads();
    int buf = 0;
    for (int k0 = 0; k0 < K; k0 += 64) {
        if (k0 + 64 < K) stage(k0 + 64, buf ^ 1);
#pragma unroll
        for (int ks = 0; ks < 2; ++ks) {
            int cswz = (ks * 32 + lk * 8) ^ ((lr & 7) << 3);
            bf16x8 af = *(bf16x8*)&As[buf * 1024 + lr * 64 + cswz];
            bf16x8 bfr = *(bf16x8*)&Bs[buf * 4096 + (w * 16 + lr) * 64 + cswz];
            acc = __builtin_amdgcn_mfma_f32_16x16x32_bf16(af, bfr, acc, 0, 0, 0);
        }
        __syncthreads();
        buf ^= 1;
    }
    float bv = bias ? bias[col0 + w * 16 + lr] : 0.f;
#pragma unroll
    for (int r = 0; r < 4; ++r) {
        float v = acc[r] + bv;
        if (RELU) v = fmaxf(v, 0.f);
        size_t ci = (size_t)(row0 + lk * 4 + r) * ldc + col0 + w * 16 + lr;
        if (OUTBF) ((__bf16*)Cv)[ci] = (__bf16)v;
        else ((float*)Cv)[ci] = v;
    }
}

// ---------------- shared epilogue: qkv cols -> qkv (Q|K) or vtb (V^T) ------
__device__ inline void qkv_epilogue(f32x4 acc[4], const float* __restrict__ bias,
                                    int gcol0, int row0, int tid,
                                    __bf16* __restrict__ qkv, __bf16* __restrict__ vtb) {
    const int w = tid >> 6, l = tid & 63, lr = l & 15, lk = l >> 4;
    if (gcol0 < 512) {
#pragma unroll
        for (int nt = 0; nt < 4; ++nt) {
            float bv = bias[gcol0 + nt * 16 + lr];
#pragma unroll
            for (int r = 0; r < 4; ++r)
                qkv[(size_t)(row0 + w * 16 + lk * 4 + r) * QKS + gcol0 + nt * 16 + lr] =
                    (__bf16)(acc[nt][r] + bv);
        }
    } else {
        const int n4 = row0 + w * 16 + lk * 4;
#pragma unroll
        for (int nt = 0; nt < 4; ++nt) {
            int dg = gcol0 - 512 + nt * 16 + lr;      // 0..255 = h*64+d
            float bv = bias[gcol0 + nt * 16 + lr];
            union { __bf16 b[4]; ushort4 u; } pk;
#pragma unroll
            for (int r = 0; r < 4; ++r) pk.b[r] = (__bf16)(acc[nt][r] + bv);
            *(ushort4*)&vtb[(size_t)dg * NN + n4] = pk.u;
        }
    }
}

// ---------------- fused: local_embed GEMM + SA qkv GEMM (one dispatch) -----
__global__ __launch_bounds__(256) void fused_local_qkv(
    const __bf16* __restrict__ hi_bf, const __bf16* __restrict__ x_bf,
    const __bf16* __restrict__ wlT, const __bf16* __restrict__ siwb,
    const float* __restrict__ sib,
    __bf16* __restrict__ local_bf, __bf16* __restrict__ qkv, __bf16* __restrict__ vtb) {
    __shared__ __align__(16) __bf16 As[2 * 4096];
    __shared__ __align__(16) __bf16 Bs[2 * 4096];
    const int tid = threadIdx.x;
    const int bx = blockIdx.x, row0 = blockIdx.y * 64;
    f32x4 acc[4] = {};
    if (bx < 4) {
        gemm_core(hi_bf, 256, wlT, 256, row0, bx * 64, 256, tid, As, Bs, acc);
        const int w = tid >> 6, l = tid & 63, lr = l & 15, lk = l >> 4;
#pragma unroll
        for (int nt = 0; nt < 4; ++nt)
#pragma unroll
            for (int r = 0; r < 4; ++r)
                local_bf[(size_t)(row0 + w * 16 + lk * 4 + r) * 256 + bx * 64 + nt * 16 + lr] =
                    (__bf16)acc[nt][r];
    } else {
        const int gcol0 = (bx - 4) * 64;
        gemm_core(x_bf, 256, siwb, 256, row0, gcol0, 256, tid, As, Bs, acc);
        qkv_epilogue(acc, sib, gcol0, row0, tid, qkv, vtb);
    }
}

// ---------------- fused: CA q-proj + CA kv-proj (one dispatch) -------------
__global__ __launch_bounds__(256) void fused_cross_proj(
    const __bf16* __restrict__ global_bf, const __bf16* __restrict__ local_bf,
    const __bf16* __restrict__ ciwb, const float* __restrict__ cib,
    __bf16* __restrict__ qkv, __bf16* __restrict__ vtb) {
    __shared__ __align__(16) __bf16 As[2 * 4096];
    __shared__ __align__(16) __bf16 Bs[2 * 4096];
    const int tid = threadIdx.x;
    const int bx = blockIdx.x, row0 = blockIdx.y * 64;
    const int gcol0 = (bx < 4) ? bx * 64 : 256 + (bx - 4) * 64;
    const __bf16* A = (bx < 4) ? global_bf : local_bf;
    f32x4 acc[4] = {};
    gemm_core(A, 256, ciwb, 256, row0, gcol0, 256, tid, As, Bs, acc);
    qkv_epilogue(acc, cib, gcol0, row0, tid, qkv, vtb);
}

// ------- flash attention, split-KV, 32x32 MFMA, 8-wave blocks --------------
// 256 queries/block (8 waves x 32q), grid (16,4,8)=512 blocks = 2/CU x 8w.
// Halves K/V staging traffic + barrier-drain events vs the 128q version.
__global__ __launch_bounds__(512, 4) void attn_split(const __bf16* __restrict__ qkvb,
                                                     const __bf16* __restrict__ Vtb,
                                                     __bf16* __restrict__ p0,
                                                     __bf16* __restrict__ p1,
                                                     __bf16* __restrict__ p2,
                                                     __bf16* __restrict__ p3,
                                                     float* __restrict__ ml) {
    const int h = blockIdx.y, s = blockIdx.z;
    const int n0 = blockIdx.x * 256;
    const int tid = threadIdx.x;
    const int w = tid >> 6, l = tid & 63;
    const int qi = l & 31, hi = l >> 5, hi8 = hi * 8;
    const int swz = (l & 7) << 3;

    // KV[0..8191] = K double-buffer; KV[8192..16383] = V double-buffer.
    __shared__ __align__(16) __bf16 KV[4 * 4096];

    const int qrow = n0 + w * 32 + qi;
    bf16x8 qf[4];   // q pre-scaled by log2e/8
#pragma unroll
    for (int d0 = 0; d0 < 4; ++d0)
        qf[d0] = *(const bf16x8*)&qkvb[(size_t)qrow * QKS + h * 64 + d0 * 16 + hi8];

    bf16x8 ones;
#pragma unroll
    for (int i = 0; i < 8; ++i) ones[i] = (__bf16)1.0f;

    f32x16 ot0 = {}, ot1 = {}, sum_acc = {};
    const __bf16* Vbh = Vtb + (size_t)h * 64 * NN;
    const int E0 = w * 512;                       // wave-uniform LDS base
    const int srow = w * 8 + (l >> 3);            // staged row 0..63
    const int scol = (l & 7) * 8;
    const int ssc = scol ^ ((srow & 7) << 3);     // pre-swizzled source col

    auto stageKV = [&](int t, int buf) {
        const int kv0 = s * KEYS_PER_SPLIT + t * 64;
        gload_lds16(qkvb + (size_t)(kv0 + srow) * QKS + 256 + h * 64 + ssc,
                    &KV[buf * 4096 + E0]);
        gload_lds16(Vbh + (size_t)srow * NN + kv0 + ssc,
                    &KV[8192 + buf * 4096 + E0]);
    };

    stageKV(0, 0);
    __syncthreads();
    int buf = 0;
    for (int t = 0; t < KEYS_PER_SPLIT / 64; ++t) {
        if (t + 1 < KEYS_PER_SPLIT / 64) stageKV(t + 1, buf ^ 1);
#pragma unroll
        for (int ss = 0; ss < 2; ++ss) {
            f32x16 st = {};
#pragma unroll
            for (int d0 = 0; d0 < 4; ++d0) {
                bf16x8 kf = *(bf16x8*)&KV[buf * 4096 + (ss * 32 + qi) * 64 + ((d0 * 16 + hi8) ^ swz)];
                st = __builtin_amdgcn_mfma_f32_32x32x16_bf16(kf, qf[d0], st, 0, 0, 0);
            }
            unsigned int wd[8];
#pragma unroll
            for (int j = 0; j < 8; ++j) {
                float a = exp2f(st[2 * j]);
                float b = exp2f(st[2 * j + 1]);
                asm("v_cvt_pk_bf16_f32 %0, %1, %2" : "=v"(wd[j]) : "v"(a), "v"(b));
            }
            asm("v_permlane32_swap_b32 %0, %1" : "+v"(wd[0]), "+v"(wd[2]));
            asm("v_permlane32_swap_b32 %0, %1" : "+v"(wd[1]), "+v"(wd[3]));
            asm("v_permlane32_swap_b32 %0, %1" : "+v"(wd[4]), "+v"(wd[6]));
            asm("v_permlane32_swap_b32 %0, %1" : "+v"(wd[5]), "+v"(wd[7]));
            union { unsigned int u[4]; bf16x8 v; } pa0, pa1;
            pa0.u[0] = wd[0]; pa0.u[1] = wd[1]; pa0.u[2] = wd[2]; pa0.u[3] = wd[3];
            pa1.u[0] = wd[4]; pa1.u[1] = wd[5]; pa1.u[2] = wd[6]; pa1.u[3] = wd[7];
            sum_acc = __builtin_amdgcn_mfma_f32_32x32x16_bf16(ones, pa0.v, sum_acc, 0, 0, 0);
            sum_acc = __builtin_amdgcn_mfma_f32_32x32x16_bf16(ones, pa1.v, sum_acc, 0, 0, 0);
#pragma unroll
            for (int kt = 0; kt < 2; ++kt) {
                bf16x8 pav = kt ? pa1.v : pa0.v;
                int colk = (ss * 32 + kt * 16 + hi8) ^ swz;
                bf16x8 vf0 = *(bf16x8*)&KV[8192 + buf * 4096 + qi * 64 + colk];
                bf16x8 vf1 = *(bf16x8*)&KV[8192 + buf * 4096 + (32 + qi) * 64 + colk];
                ot0 = __builtin_amdgcn_mfma_f32_32x32x16_bf16(vf0, pav, ot0, 0, 0, 0);
                ot1 = __builtin_amdgcn_mfma_f32_32x32x16_bf16(vf1, pav, ot1, 0, 0, 0);
            }
        }
        __syncthreads();
        buf ^= 1;
    }

    float tot = sum_acc[0];   // every D-row of (ones @ P^T) equals the q-sum
    __bf16* pb;
    switch (s >> 1) {
        case 0: pb = p0; break;
        case 1: pb = p1; break;
        case 2: pb = p2; break;
        default: pb = p3; break;
    }
    pb += (size_t)(s & 1) * NHEAD * NN * 64;

    // O^T regs -> wave-local LDS (swizzled), then 1KB-contiguous global stores
    __bf16* lw = &KV[w * 2048];      // whole KV dead after the loop
    const int sw = (qi & 7) << 3;
#pragma unroll
    for (int r = 0; r < 16; r += 2) {
        int d = (r & 3) + 8 * (r >> 2) + 4 * hi;   // even; pairs (d, d+1)
        union { unsigned int u; __bf16 b[2]; } w2, w3;
        w2.b[0] = (__bf16)ot0[r]; w2.b[1] = (__bf16)ot0[r + 1];
        w3.b[0] = (__bf16)ot1[r]; w3.b[1] = (__bf16)ot1[r + 1];
        *(unsigned int*)&lw[qi * 64 + (d ^ sw)] = w2.u;
        *(unsigned int*)&lw[qi * 64 + ((d + 32) ^ sw)] = w3.u;
    }
    if (hi == 0) ml[((size_t)s * NHEAD + h) * NN + qrow] = tot;
    __syncthreads();
    __bf16* gdst = pb + ((size_t)h * NN + n0 + w * 32) * 64;
#pragma unroll
    for (int j = 0; j < 4; ++j) {
        int q = (l >> 3) + j * 8;
        int x = (l & 7) * 8;
        bf16x8 v = *(bf16x8*)&lw[q * 64 + (x ^ ((q & 7) << 3))];
        *(bf16x8*)&gdst[q * 64 + x] = v;
    }
}

// ---------------- merge: core[n][h*64+d] = sum_s part / sum_s l ------------
__global__ __launch_bounds__(256) void attn_merge(const __bf16* __restrict__ p0,
                                                  const __bf16* __restrict__ p1,
                                                  const __bf16* __restrict__ p2,
                                                  const __bf16* __restrict__ p3,
                                                  const float* __restrict__ ml,
                                                  __bf16* __restrict__ coreb) {
    int g = blockIdx.x * 256 + threadIdx.x;     // 0 .. NHEAD*NN*8-1
    int d8 = g & 7;
    int hn = g >> 3;                            // h*NN + n
    int n = hn & (NN - 1), h = hn >> 12;
    float L = 0.f;
    float o[8] = {};
#pragma unroll
    for (int s = 0; s < NSPLIT; ++s) {
        const __bf16* pb = (s < 2 ? p0 : s < 4 ? p1 : s < 6 ? p2 : p3) +
                           (size_t)(s & 1) * NHEAD * NN * 64;
        bf16x8 v = *(const bf16x8*)&pb[(size_t)hn * 64 + d8 * 8];
#pragma unroll
        for (int j = 0; j < 8; ++j) o[j] += (float)v[j];
        L += ml[((size_t)s * NHEAD + h) * NN + n];
    }
    float inv = 1.f / L;
    bf16x8 r;
#pragma unroll
    for (int j = 0; j < 8; ++j) r[j] = (__bf16)(o[j] * inv);
    *(bf16x8*)&coreb[(size_t)n * 256 + h * 64 + d8 * 8] = r;
}

// ---------------- LayerNorm(a + b) -> fp32 and/or bf16 ----------------
__device__ inline float block_sum256(float v, float* tmp) {
#pragma unroll
    for (int o = 32; o; o >>= 1) v += __shfl_xor(v, o);
    __syncthreads();
    if ((threadIdx.x & 63) == 0) tmp[threadIdx.x >> 6] = v;
    __syncthreads();
    return tmp[0] + tmp[1] + tmp[2] + tmp[3];
}

__global__ __launch_bounds__(256) void ln_kernel(const float* __restrict__ a,
                                                 const float* __restrict__ b,
                                                 const float* __restrict__ g,
                                                 const float* __restrict__ be,
                                                 float* __restrict__ outf,
                                                 __bf16* __restrict__ outb) {
    __shared__ float tmp[4];
    const int n = blockIdx.x, t = threadIdx.x;
    float v = a[n * EDIM + t] + b[n * EDIM + t];
    float mean = block_sum256(v, tmp) * (1.f / 256.f);
    float c = v - mean;
    float var = block_sum256(c * c, tmp) * (1.f / 256.f);
    float o = c * (1.f / sqrtf(var + 1e-5f)) * g[t] + be[t];
    if (outf) outf[n * EDIM + t] = o;
    if (outb) outb[n * EDIM + t] = (__bf16)o;
}

extern "C" void kernel_launch(void* const* d_in, const int* in_sizes, int n_in,
                              void* d_out, int out_size, void* d_ws, size_t ws_size,
                              hipStream_t stream) {
    const float* x = (const float*)d_in[0];
    const int* ei = (const int*)d_in[1];
    const float* w_local = (const float*)d_in[2];
    const float* sa_in_w = (const float*)d_in[3];
    const float* sa_in_b = (const float*)d_in[4];
    const float* sa_out_w = (const float*)d_in[5];
    const float* sa_out_b = (const float*)d_in[6];
    const float* ln1_g = (const float*)d_in[7];
    const float* ln1_b = (const float*)d_in[8];
    const float* ca_in_w = (const float*)d_in[9];
    const float* ca_in_b = (const float*)d_in[10];
    const float* ca_out_w = (const float*)d_in[11];
    const float* ca_out_b = (const float*)d_in[12];
    const float* ln2_g = (const float*)d_in[13];
    const float* ln2_b = (const float*)d_in[14];
    const float* gate_w = (const float*)d_in[15];
    const float* gate_b = (const float*)d_in[16];
    const float* fc_w = (const float*)d_in[17];
    const float* fc_b = (const float*)d_in[18];
    float* out = (float*)d_out;

    float* ws = (float*)d_ws;
    float* dnz = ws;                                   // 4096
    float* ml = ws + 4096;                             // 131072
    __bf16* x_bf = (__bf16*)(ml + 131072);             // NE bf16
    __bf16* hi_bf = (__bf16*)((float*)x_bf + NE / 2);  // NE bf16
    __bf16* local_bf = (__bf16*)((float*)hi_bf + NE / 2);
    __bf16* qkv_bf = (__bf16*)((float*)local_bf + NE / 2);  // 2*NE bf16 (stride 512)
    __bf16* core_bf = (__bf16*)((float*)qkv_bf + 3 * NE / 2);
    float* proj = (float*)core_bf + NE / 2;            // NE f32
    float* global_f = proj + NE;                       // NE f32
    __bf16* global_bf = (__bf16*)(global_f + NE);      // NE bf16
    __bf16* aligned_bf = (__bf16*)((float*)global_bf + NE / 2);
    __bf16* fin_bf = (__bf16*)((float*)aligned_bf + NE / 2);
    __bf16* vtb = (__bf16*)((float*)fin_bf + NE / 2);  // NHEAD*NN*64 bf16
    __bf16* siwb = (__bf16*)((float*)vtb + NE / 2);    // 196608
    __bf16* ciwb = siwb + 196608;
    __bf16* sowb = ciwb + 196608;
    __bf16* cowb = sowb + 65536;
    __bf16* gwb = cowb + 65536;
    __bf16* fwb = gwb + 131072;
    __bf16* wlT = fwb + 65536;
    float* sib_adj = (float*)(wlT + 65536);
    float* cib_adj = sib_adj + 768;

    // CSR scratch overlays qkv region (dead until in-proj GEMMs)
    int* degi = (int*)qkv_bf;
    int* off = degi + 4096;
    int* cursor = off + 4096;
    int* rows = cursor + 4096;

    // attention split partials: 4 regions x 2 splits x 2MB ([h][n][64] each)
    __bf16* pA = (__bf16*)out;
    __bf16* pB = x_bf;
    __bf16* pC = (__bf16*)proj;
    __bf16* pD = aligned_bf;

    // ---- prep (weights/x -> bf16, degi zero) ----
    prep_kernel<<<7190, 256, 0, stream>>>(w_local, sa_in_w, sa_in_b, sa_out_w,
                                          ca_in_w, ca_in_b, ca_out_w, gate_w, fc_w, x,
                                          siwb, ciwb, sowb, cowb, gwb, fwb, wlT, x_bf,
                                          sib_adj, cib_adj, degi);

    // ---- GCN via CSR gather (bf16 x) ----
    degi_kernel<<<NEDGE / 256, 256, 0, stream>>>(ei, degi, NEDGE);
    scan_kernel<<<1, 256, 0, stream>>>(degi, off, cursor, dnz);
    fill_kernel<<<NEDGE / 256, 256, 0, stream>>>(ei, cursor, rows, NEDGE);
    gather_kernel<<<NN, 256, 0, stream>>>(off, rows, dnz, x_bf, hi_bf);

    // ---- local_embed GEMM + SA in-proj (fused dispatch; V -> vtb direct) ----
    fused_local_qkv<<<dim3(16, 64), 256, 0, stream>>>(
        hi_bf, x_bf, wlT, siwb, sib_adj, local_bf, qkv_bf, vtb);
    attn_split<<<dim3(NN / 256, NHEAD, NSPLIT), 512, 0, stream>>>(qkv_bf, vtb, pA, pB, pC, pD, ml);
    attn_merge<<<512, 256, 0, stream>>>(pA, pB, pC, pD, ml, core_bf);
    gemm_thin<false, false><<<dim3(4, 256), 256, 0, stream>>>(
        core_bf, nullptr, 256, sowb, 256, sa_out_b, proj, 256, 256);
    ln_kernel<<<NN, 256, 0, stream>>>(x, proj, ln1_g, ln1_b, global_f, global_bf);

    // ---- CA in-proj (fused q+kv dispatch) ----
    fused_cross_proj<<<dim3(12, 64), 256, 0, stream>>>(
        global_bf, local_bf, ciwb, cib_adj, qkv_bf, vtb);
    attn_split<<<dim3(NN / 256, NHEAD, NSPLIT), 512, 0, stream>>>(qkv_bf, vtb, pA, pB, pC, pD, ml);
    attn_merge<<<512, 256, 0, stream>>>(pA, pB, pC, pD, ml, core_bf);
    gemm_thin<false, false><<<dim3(4, 256), 256, 0, stream>>>(
        core_bf, nullptr, 256, cowb, 256, ca_out_b, proj, 256, 256);
    ln_kernel<<<NN, 256, 0, stream>>>(global_f, proj, ln2_g, ln2_b, nullptr, aligned_bf);

    // ---- gated head (concat via A/A2 switch) ----
    gemm_thin<true, true><<<dim3(4, 256), 256, 0, stream>>>(
        global_bf, aligned_bf, 256, gwb, 512, gate_b, fin_bf, 256, 512);
    gemm_thin<false, false><<<dim3(4, 256), 256, 0, stream>>>(
        fin_bf, nullptr, 256, fwb, 256, fc_b, out, 256, 256);
}